// Round 7
// baseline (208.541 us; speedup 1.0000x reference)
//
#include <hip/hip_runtime.h>
#include <cstdint>
#include <cstddef>

#define BB 16
#define NN 4096
#define EE 131072
#define CIN 256
#define COUT 256
#define NCH 16
#define CHE (EE / NCH)   // 8192 edges per chunk

typedef __attribute__((ext_vector_type(8))) __bf16 bf16x8;
typedef __attribute__((ext_vector_type(4))) float f32x4;
typedef __attribute__((ext_vector_type(2))) float f32x2;

#define GLDS16(g, l) __builtin_amdgcn_global_load_lds( \
    (const __attribute__((address_space(1))) uint32_t*)(g), \
    (__attribute__((address_space(3))) uint32_t*)(l), 16, 0, 0)

// ---------------- W transpose + bf16 cast: wt[n][k] = (bf16)W[k][n] ----------------
__global__ __launch_bounds__(256) void cvt_wt_kernel(const float* __restrict__ W, __bf16* __restrict__ wt) {
    int n = blockIdx.x;
    int k = threadIdx.x;
    wt[n * CIN + k] = (__bf16)W[(size_t)k * COUT + n];
}

// ---------------- phase A: hist (256 blocks) ∥ x->bf16 cvt (8192 blocks) ----------------
__global__ __launch_bounds__(256) void phaseA_kernel(const float* __restrict__ x, __bf16* __restrict__ xbf,
                                                     const int* __restrict__ ei, const float* __restrict__ ew,
                                                     int* __restrict__ chist, float* __restrict__ wdeg) {
    __shared__ int h[NN];       // 16 KB
    __shared__ float wh[NN];    // 16 KB
    int bid = blockIdx.x;
    int tid = threadIdx.x;
    if (bid < BB * NCH) {
        int b = bid >> 4, c = bid & (NCH - 1);
        for (int i = tid; i < NN; i += 256) { h[i] = 0; wh[i] = 0.f; }
        __syncthreads();
        const int* rows = ei + (size_t)b * 2 * EE + (size_t)c * CHE;
        const float* w = ew + (size_t)b * EE + (size_t)c * CHE;
        #pragma unroll 4
        for (int j = 0; j < CHE / 256; ++j) {
            int row = rows[j * 256 + tid];
            float wv = w[j * 256 + tid];
            atomicAdd(&h[row], 1);
            atomicAdd(&wh[row], wv);
        }
        __syncthreads();
        int* co = chist + ((size_t)b * NCH + c) * NN;
        float* wo = wdeg + ((size_t)b * NCH + c) * NN;
        for (int i = tid; i < NN; i += 256) { co[i] = h[i]; wo[i] = wh[i]; }
    } else {
        size_t u = (size_t)(bid - BB * NCH) * 256 + tid;  // 8-elem unit, 2,097,152 total
        const float* g = &x[u * 8];
        float4 f0 = *reinterpret_cast<const float4*>(g);
        float4 f1 = *reinterpret_cast<const float4*>(g + 4);
        bf16x8 v;
        v[0] = (__bf16)f0.x; v[1] = (__bf16)f0.y; v[2] = (__bf16)f0.z; v[3] = (__bf16)f0.w;
        v[4] = (__bf16)f1.x; v[5] = (__bf16)f1.y; v[6] = (__bf16)f1.z; v[7] = (__bf16)f1.w;
        *reinterpret_cast<bf16x8*>(&xbf[u * 8]) = v;
    }
}

// ---------------- row totals + dinv (full-chip parallel) ----------------
__global__ __launch_bounds__(256) void rowstat_kernel(const int* __restrict__ chist, const float* __restrict__ wdeg,
                                                      int* __restrict__ rowtot, float* __restrict__ dinv) {
    int gid = blockIdx.x * 256 + threadIdx.x;   // 65536
    int b = gid >> 12, r = gid & (NN - 1);
    int tot = 0;
    float dsum = 1.0f;   // +1 self loop, always > 0
    #pragma unroll
    for (int c = 0; c < NCH; ++c) {
        size_t idx = ((size_t)b * NCH + c) * NN + r;
        tot += chist[idx];
        dsum += wdeg[idx];
    }
    rowtot[gid] = tot;
    dinv[gid] = rsqrtf(dsum);
}

// ---------------- per-batch exclusive scan of row totals (16 KB per block) ----------------
__global__ __launch_bounds__(1024) void scan3_kernel(const int* __restrict__ rowtot, int* __restrict__ roff) {
    int b = blockIdx.x, tid = threadIdx.x;
    int wid = tid >> 6, lane = tid & 63;
    __shared__ int wsum[16];
    __shared__ int wbase[16];
    __shared__ int gtot_s;
    int carry = 0;
    for (int g = 0; g < 4; ++g) {
        int r = g * 1024 + tid;
        int tot = rowtot[b * NN + r];
        int incl = tot;
        #pragma unroll
        for (int off = 1; off < 64; off <<= 1) {
            int t = __shfl_up(incl, off, 64);
            if (lane >= off) incl += t;
        }
        if (lane == 63) wsum[wid] = incl;
        __syncthreads();
        if (wid == 0) {
            int v = (lane < 16) ? wsum[lane] : 0;
            int winc = v;
            #pragma unroll
            for (int off = 1; off < 16; off <<= 1) {
                int t = __shfl_up(winc, off, 64);
                if (lane >= off) winc += t;
            }
            if (lane < 16) wbase[lane] = winc - v;
            if (lane == 15) gtot_s = winc;
        }
        __syncthreads();
        roff[b * NN + r] = carry + wbase[wid] + (incl - tot);
        carry += gtot_s;
        __syncthreads();
    }
}

// ---------------- per-chunk CSR bases (full-chip parallel) ----------------
__global__ __launch_bounds__(256) void chunkbase_kernel(const int* __restrict__ chist, const int* __restrict__ roff,
                                                        int* __restrict__ chunkbase) {
    int gid = blockIdx.x * 256 + threadIdx.x;
    int b = gid >> 12, r = gid & (NN - 1);
    int acc = roff[gid];
    #pragma unroll
    for (int c = 0; c < NCH; ++c) {
        size_t idx = ((size_t)b * NCH + c) * NN + r;
        int t = chist[idx];
        chunkbase[idx] = acc;
        acc += t;
    }
}

// ---------------- scatter into CSR slots — LDS atomics only, XCD-pinned ----------------
__global__ __launch_bounds__(256) void scatter2_kernel(const int* __restrict__ ei, const float* __restrict__ ew,
                                                       const float* __restrict__ dinv, const int* __restrict__ chunkbase,
                                                       int2* __restrict__ csr) {
    __shared__ int basebuf[NN];     // 16 KB
    __shared__ float dinvs[NN];     // 16 KB
    int bid = blockIdx.x;           // 256 blocks
    int xcd = bid & 7;
    int j = bid >> 3;
    int b = xcd * 2 + (j >> 4);
    int c = j & (NCH - 1);
    int tid = threadIdx.x;
    for (int i = tid; i < NN; i += 256) {
        basebuf[i] = chunkbase[((size_t)b * NCH + c) * NN + i];
        dinvs[i] = dinv[b * NN + i];
    }
    __syncthreads();
    const int* rows = ei + (size_t)b * 2 * EE + (size_t)c * CHE;
    const int* cols = rows + EE;
    const float* w = ew + (size_t)b * EE + (size_t)c * CHE;
    int2* cs = csr + (size_t)b * EE;
    #pragma unroll 4
    for (int jj = 0; jj < CHE / 256; ++jj) {
        int e = jj * 256 + tid;
        int row = rows[e];
        int col = cols[e];
        float nm = dinvs[row] * w[e] * dinvs[col];
        int pos = atomicAdd(&basebuf[row], 1);
        int2 pk; pk.x = col * (COUT * 2); pk.y = __float_as_int(nm);
        cs[pos] = pk;
    }
}

// ---------------- MFMA GEMM via global_load_lds: xw(bf16) = xbf @ wt^T ----------------
__global__ __launch_bounds__(256) void gemm_glds_kernel(const __bf16* __restrict__ xbf, const __bf16* __restrict__ wt,
                                                        __bf16* __restrict__ xw) {
    __shared__ __bf16 As[128 * 64];   // 16 KB, layout [r][k]
    __shared__ __bf16 Bs[128 * 64];   // 16 KB, layout [c][k]
    int tid = threadIdx.x;
    int lane = tid & 63;
    int wave = tid >> 6;
    int bx = blockIdx.x >> 1, by = blockIdx.x & 1;   // 1024 blocks -> (512, 2)
    int row0 = bx * 128, col0 = by * 128;
    int wr = wave >> 1, wc = wave & 1;
    int hi = lane >> 4, lo = lane & 15;
    int lr = lane >> 3, lk = (lane & 7) * 8;
    f32x4 acc[4][4] = {};

    for (int kk = 0; kk < CIN; kk += 64) {
        #pragma unroll
        for (int j = 0; j < 4; ++j) {
            int seg = j * 4 + wave;
            const __bf16* ga = &xbf[(size_t)(row0 + seg * 8 + lr) * CIN + kk + lk];
            const __bf16* gb = &wt [(size_t)(col0 + seg * 8 + lr) * CIN + kk + lk];
            GLDS16(ga, &As[seg * 512]);
            GLDS16(gb, &Bs[seg * 512]);
        }
        __syncthreads();
        #pragma unroll
        for (int ks = 0; ks < 2; ++ks) {
            bf16x8 a[4], b[4];
            #pragma unroll
            for (int m = 0; m < 4; ++m)
                a[m] = *reinterpret_cast<const bf16x8*>(&As[(wr * 64 + m * 16 + lo) * 64 + ks * 32 + 8 * hi]);
            #pragma unroll
            for (int n = 0; n < 4; ++n)
                b[n] = *reinterpret_cast<const bf16x8*>(&Bs[(wc * 64 + n * 16 + lo) * 64 + ks * 32 + 8 * hi]);
            #pragma unroll
            for (int m = 0; m < 4; ++m)
                #pragma unroll
                for (int n = 0; n < 4; ++n)
                    acc[m][n] = __builtin_amdgcn_mfma_f32_16x16x32_bf16(a[m], b[n], acc[m][n], 0, 0, 0);
        }
        __syncthreads();
    }
    #pragma unroll
    for (int m = 0; m < 4; ++m)
        #pragma unroll
        for (int n = 0; n < 4; ++n)
            #pragma unroll
            for (int r = 0; r < 4; ++r) {
                int row = row0 + wr * 64 + m * 16 + hi * 4 + r;
                int col = col0 + wc * 64 + n * 16 + lo;
                xw[(size_t)row * COUT + col] = (__bf16)acc[m][n][r];
            }
}

// ---------------- CSR aggregation v4: 2 waves/row (edge-split) + 2-stage pipeline ----------------
#define EDGE_FMA(nmbits, raw) { \
    float nm_ = __int_as_float(nmbits); \
    f32x2 v01_, v23_; \
    v01_.x = __uint_as_float((raw).x << 16); \
    v01_.y = __uint_as_float((raw).x & 0xffff0000u); \
    v23_.x = __uint_as_float((raw).y << 16); \
    v23_.y = __uint_as_float((raw).y & 0xffff0000u); \
    acc01 += nm_ * v01_; \
    acc23 += nm_ * v23_; }

__global__ __launch_bounds__(256) void aggregate_kernel(const __bf16* __restrict__ xw, const float* __restrict__ dinv,
                                                        const int* __restrict__ roff, const int2* __restrict__ csr,
                                                        float* __restrict__ out) {
    __shared__ float4 part[2][64];   // 2 KB — wave-1 partials
    int bid = blockIdx.x;            // 32768 blocks
    int xcd = bid & 7;
    int idx = bid >> 3;              // 0..4095
    int b = xcd * 2 + (idx >> 11);
    int rowpair = idx & 2047;
    int tid = threadIdx.x;
    int wave = tid >> 6;
    int lane = tid & 63;
    int rloc = wave >> 1;            // row within block (0..1)
    int half = wave & 1;             // 0: first-half edges + self, 1: second half
    int n = rowpair * 2 + rloc;

    int s = __builtin_amdgcn_readfirstlane(roff[b * NN + n]);
    int eRaw = (n == NN - 1) ? EE : roff[b * NN + n + 1];
    int e = __builtin_amdgcn_readfirstlane(eRaw);
    int cnt = e - s;
    int h0 = (cnt + 1) >> 1;
    int lo = half ? h0 : 0;
    int sub = (half ? cnt : h0) - lo;
    const int2* cs = csr + (size_t)b * EE + s + lo;

    const char* xwb = (const char*)(xw + (size_t)b * NN * COUT) + lane * 8;
    f32x2 acc01 = {0.f, 0.f}, acc23 = {0.f, 0.f};
    if (half == 0) {
        float di = dinv[b * NN + n];
        float sn = di * di;
        uint2 sraw = *reinterpret_cast<const uint2*>(xwb + n * (COUT * 2));
        acc01.x = sn * __uint_as_float(sraw.x << 16);
        acc01.y = sn * __uint_as_float(sraw.x & 0xffff0000u);
        acc23.x = sn * __uint_as_float(sraw.y << 16);
        acc23.y = sn * __uint_as_float(sraw.y & 0xffff0000u);
    }

    int i = 0;
    if (sub >= 8) {
        int2 q0[8];
        uint2 r0[8];
        #pragma unroll
        for (int u = 0; u < 8; ++u) q0[u] = cs[u];          // wave-uniform -> scalar loads
        #pragma unroll
        for (int u = 0; u < 8; ++u) r0[u] = *reinterpret_cast<const uint2*>(xwb + q0[u].x);
        for (i = 8; i + 8 <= sub; i += 8) {
            int2 q1[8];
            uint2 r1[8];
            #pragma unroll
            for (int u = 0; u < 8; ++u) q1[u] = cs[i + u];  // prefetch next chunk
            #pragma unroll
            for (int u = 0; u < 8; ++u) r1[u] = *reinterpret_cast<const uint2*>(xwb + q1[u].x);
            #pragma unroll
            for (int u = 0; u < 8; ++u) EDGE_FMA(q0[u].y, r0[u]);   // consume current
            #pragma unroll
            for (int u = 0; u < 8; ++u) { q0[u] = q1[u]; r0[u] = r1[u]; }
        }
        #pragma unroll
        for (int u = 0; u < 8; ++u) EDGE_FMA(q0[u].y, r0[u]);
    }
    if (i < sub) {   // clamped tail (sub >= 1 here; padding lanes use norm=0)
        #pragma unroll
        for (int u = 0; u < 8; ++u) {
            int j = i + u;
            int jj = (j < sub) ? j : (sub - 1);
            int2 q = cs[jj];
            float nmb = (j < sub) ? __int_as_float(q.y) : 0.0f;
            uint2 raw = *reinterpret_cast<const uint2*>(xwb + q.x);
            EDGE_FMA(__float_as_int(nmb), raw);
        }
    }

    if (half == 1) part[rloc][lane] = make_float4(acc01.x, acc01.y, acc23.x, acc23.y);
    __syncthreads();
    if (half == 0) {
        float4 p = part[rloc][lane];
        float4 o = make_float4(fmaxf(acc01.x + p.x, 0.f), fmaxf(acc01.y + p.y, 0.f),
                               fmaxf(acc23.x + p.z, 0.f), fmaxf(acc23.y + p.w, 0.f));
        *reinterpret_cast<float4*>(&out[((size_t)b * NN + n) * COUT + 4 * lane]) = o;
    }
}

// ---------------- fallback (atomic) path ----------------
__global__ __launch_bounds__(256) void init_deg_kernel(float* __restrict__ deg, float v) {
    int i = blockIdx.x * 256 + threadIdx.x;
    if (i < BB * NN) deg[i] = v;
}

__global__ __launch_bounds__(256) void deg_only_kernel(const int* __restrict__ ei, const float* __restrict__ ew,
                                                       float* __restrict__ deg) {
    int idx = blockIdx.x * 256 + threadIdx.x;
    if (idx >= BB * EE) return;
    int b = idx / EE, e = idx - b * EE;
    atomicAdd(&deg[b * NN + ei[(size_t)b * 2 * EE + e]], ew[(size_t)b * EE + e]);
}

__global__ __launch_bounds__(256) void deginv_kernel(const float* __restrict__ deg, float* __restrict__ dinv) {
    int i = blockIdx.x * 256 + threadIdx.x;
    if (i < BB * NN) {
        float d = deg[i];
        dinv[i] = (d > 0.0f) ? rsqrtf(d) : 0.0f;
    }
}

__global__ __launch_bounds__(256) void gemm_f32src_kernel(const float* __restrict__ x, const __bf16* __restrict__ wt,
                                                          __bf16* __restrict__ xw) {
    __shared__ __bf16 As[128][64];
    __shared__ __bf16 Bs[128][64];
    int tid = threadIdx.x;
    int lane = tid & 63;
    int wave = tid >> 6;
    int row0 = blockIdx.x * 128;
    int col0 = blockIdx.y * 128;
    int wr = wave >> 1, wc = wave & 1;
    int hi = lane >> 4, lo = lane & 15;
    f32x4 acc[4][4] = {};
    for (int kk = 0; kk < CIN; kk += 64) {
        #pragma unroll
        for (int j = 0; j < 4; ++j) {
            int c = j * 256 + tid;
            int r = c >> 3, kq = c & 7;
            const float* g = &x[(size_t)(row0 + r) * CIN + kk + 8 * kq];
            float4 f0 = *reinterpret_cast<const float4*>(g);
            float4 f1 = *reinterpret_cast<const float4*>(g + 4);
            bf16x8 v;
            v[0] = (__bf16)f0.x; v[1] = (__bf16)f0.y; v[2] = (__bf16)f0.z; v[3] = (__bf16)f0.w;
            v[4] = (__bf16)f1.x; v[5] = (__bf16)f1.y; v[6] = (__bf16)f1.z; v[7] = (__bf16)f1.w;
            *reinterpret_cast<bf16x8*>(&As[r][8 * kq]) = v;
        }
        #pragma unroll
        for (int j = 0; j < 4; ++j) {
            int c = j * 256 + tid;
            int r = c >> 3, kq = c & 7;
            *reinterpret_cast<bf16x8*>(&Bs[r][8 * kq]) =
                *reinterpret_cast<const bf16x8*>(&wt[(size_t)(col0 + r) * CIN + kk + 8 * kq]);
        }
        __syncthreads();
        #pragma unroll
        for (int ks = 0; ks < 2; ++ks) {
            bf16x8 a[4], b[4];
            #pragma unroll
            for (int m = 0; m < 4; ++m)
                a[m] = *reinterpret_cast<const bf16x8*>(&As[wr * 64 + m * 16 + lo][ks * 32 + 8 * hi]);
            #pragma unroll
            for (int n = 0; n < 4; ++n)
                b[n] = *reinterpret_cast<const bf16x8*>(&Bs[wc * 64 + n * 16 + lo][ks * 32 + 8 * hi]);
            #pragma unroll
            for (int m = 0; m < 4; ++m)
                #pragma unroll
                for (int n = 0; n < 4; ++n)
                    acc[m][n] = __builtin_amdgcn_mfma_f32_16x16x32_bf16(a[m], b[n], acc[m][n], 0, 0, 0);
        }
        __syncthreads();
    }
    #pragma unroll
    for (int m = 0; m < 4; ++m)
        #pragma unroll
        for (int n = 0; n < 4; ++n)
            #pragma unroll
            for (int r = 0; r < 4; ++r) {
                int row = row0 + wr * 64 + m * 16 + hi * 4 + r;
                int col = col0 + wc * 64 + n * 16 + lo;
                xw[(size_t)row * COUT + col] = (__bf16)acc[m][n][r];
            }
}

__global__ __launch_bounds__(256) void self_kernel(const __bf16* __restrict__ xw, const float* __restrict__ dinv,
                                                   float* __restrict__ out) {
    int bn = blockIdx.x;
    int c = threadIdx.x;
    float di = dinv[bn];
    out[(size_t)bn * COUT + c] = di * di * (float)xw[(size_t)bn * COUT + c];
}

__global__ __launch_bounds__(256) void scatter_atomic_kernel(const int* __restrict__ ei, const float* __restrict__ ew,
                                                             const float* __restrict__ dinv,
                                                             const __bf16* __restrict__ xw, float* __restrict__ out) {
    int be = blockIdx.x;
    int b = be / EE, e = be - b * EE;
    int c = threadIdx.x;
    int row = ei[(size_t)b * 2 * EE + e];
    int col = ei[(size_t)b * 2 * EE + EE + e];
    float w = ew[(size_t)b * EE + e];
    float nm = dinv[b * NN + row] * w * dinv[b * NN + col];
    const __bf16* xwb = xw + (size_t)b * NN * COUT;
    atomicAdd(&out[((size_t)b * NN + row) * COUT + c], nm * (float)xwb[(size_t)col * COUT + c]);
}

__global__ __launch_bounds__(256) void relu_kernel(float* __restrict__ out) {
    size_t i = (size_t)blockIdx.x * 256 + threadIdx.x;
    out[i] = fmaxf(out[i], 0.0f);
}

extern "C" void kernel_launch(void* const* d_in, const int* in_sizes, int n_in,
                              void* d_out, int out_size, void* d_ws, size_t ws_size,
                              hipStream_t stream) {
    const float* x  = (const float*)d_in[0];
    const int*   ei = (const int*)d_in[1];
    const float* ew = (const float*)d_in[2];
    const float* Wm = (const float*)d_in[3];
    float* out = (float*)d_out;

    char* ws = (char*)d_ws;
    size_t off = 0;
    auto alloc = [&](size_t bytes) -> void* {
        void* p = ws + off;
        off += (bytes + 255) & ~(size_t)255;
        return p;
    };
    __bf16* xw        = (__bf16*)alloc((size_t)BB * NN * COUT * 2);   // 32 MB
    __bf16* xbf       = (__bf16*)alloc((size_t)BB * NN * CIN * 2);    // 32 MB
    int*    chist     = (int*)alloc((size_t)BB * NCH * NN * 4);       // 4 MB
    float*  wdeg      = (float*)alloc((size_t)BB * NCH * NN * 4);     // 4 MB
    int*    chunkbase = (int*)alloc((size_t)BB * NCH * NN * 4);       // 4 MB
    int*    roff      = (int*)alloc((size_t)BB * NN * 4);             // 256 KB
    float*  dinv      = (float*)alloc((size_t)BB * NN * 4);           // 256 KB
    __bf16* wt        = (__bf16*)alloc((size_t)CIN * COUT * 2);
    int2*   csr       = (int2*)xbf;        // alias: xbf dead after gemm, csr written after
    int*    rowtot    = (int*)chunkbase;   // alias: rowtot dead before chunkbase written
    float*  deg_fb    = (float*)chist;     // fallback-only alias
    bool use_csr = (ws_size >= off);

    cvt_wt_kernel<<<COUT, CIN, 0, stream>>>(Wm, wt);

    if (use_csr) {
        phaseA_kernel<<<BB * NCH + (BB * NN * CIN) / (256 * 8), 256, 0, stream>>>(x, xbf, ei, ew, chist, wdeg);
        rowstat_kernel<<<(BB * NN) / 256, 256, 0, stream>>>(chist, wdeg, rowtot, dinv);
        scan3_kernel<<<BB, 1024, 0, stream>>>(rowtot, roff);
        chunkbase_kernel<<<(BB * NN) / 256, 256, 0, stream>>>(chist, roff, chunkbase);
        gemm_glds_kernel<<<(BB * NN / 128) * (COUT / 128), 256, 0, stream>>>(xbf, wt, xw);
        scatter2_kernel<<<BB * NCH, 256, 0, stream>>>(ei, ew, dinv, chunkbase, csr);
        aggregate_kernel<<<BB * NN / 2, 256, 0, stream>>>(xw, dinv, roff, csr, out);
    } else {
        const int bnBlocks = (BB * NN) / 256;
        init_deg_kernel<<<bnBlocks, 256, 0, stream>>>(deg_fb, 1.0f);
        deg_only_kernel<<<(BB * EE) / 256, 256, 0, stream>>>(ei, ew, deg_fb);
        deginv_kernel<<<bnBlocks, 256, 0, stream>>>(deg_fb, dinv);
        dim3 ggrid((BB * NN) / 128, COUT / 128);
        gemm_f32src_kernel<<<ggrid, 256, 0, stream>>>(x, wt, xw);
        self_kernel<<<BB * NN, 256, 0, stream>>>(xw, dinv, out);
        scatter_atomic_kernel<<<BB * EE, 256, 0, stream>>>(ei, ew, dinv, xw, out);
        relu_kernel<<<(BB * NN * COUT) / 256, 256, 0, stream>>>(out);
    }
}

// Round 8
// 158.219 us; speedup vs baseline: 1.3181x; 1.3181x over previous
//
#include <hip/hip_runtime.h>
#include <cstdint>
#include <cstddef>

#define BB 16
#define NN 4096
#define EE 131072
#define CIN 256
#define COUT 256
#define NCH 16
#define CHE (EE / NCH)   // 8192 edges per chunk

typedef __attribute__((ext_vector_type(8))) __bf16 bf16x8;
typedef __attribute__((ext_vector_type(4))) float f32x4;
typedef __attribute__((ext_vector_type(2))) float f32x2;

#define GLDS16(g, l) __builtin_amdgcn_global_load_lds( \
    (const __attribute__((address_space(1))) uint32_t*)(g), \
    (__attribute__((address_space(3))) uint32_t*)(l), 16, 0, 0)

// ---------------- W transpose + bf16 cast: wt[n][k] = (bf16)W[k][n] ----------------
__global__ __launch_bounds__(256) void cvt_wt_kernel(const float* __restrict__ W, __bf16* __restrict__ wt) {
    int n = blockIdx.x;
    int k = threadIdx.x;
    wt[n * CIN + k] = (__bf16)W[(size_t)k * COUT + n];
}

// ---------------- phase A: hist (256 blocks) ∥ x->bf16 cvt (8192 blocks) ----------------
__global__ __launch_bounds__(256) void phaseA_kernel(const float* __restrict__ x, __bf16* __restrict__ xbf,
                                                     const int* __restrict__ ei, const float* __restrict__ ew,
                                                     int* __restrict__ chist, float* __restrict__ wdeg) {
    __shared__ int h[NN];       // 16 KB
    __shared__ float wh[NN];    // 16 KB
    int bid = blockIdx.x;
    int tid = threadIdx.x;
    if (bid < BB * NCH) {
        int b = bid >> 4, c = bid & (NCH - 1);
        for (int i = tid; i < NN; i += 256) { h[i] = 0; wh[i] = 0.f; }
        __syncthreads();
        const int* rows = ei + (size_t)b * 2 * EE + (size_t)c * CHE;
        const float* w = ew + (size_t)b * EE + (size_t)c * CHE;
        #pragma unroll 4
        for (int j = 0; j < CHE / 256; ++j) {
            int row = rows[j * 256 + tid];
            float wv = w[j * 256 + tid];
            atomicAdd(&h[row], 1);
            atomicAdd(&wh[row], wv);
        }
        __syncthreads();
        int* co = chist + ((size_t)b * NCH + c) * NN;
        float* wo = wdeg + ((size_t)b * NCH + c) * NN;
        for (int i = tid; i < NN; i += 256) { co[i] = h[i]; wo[i] = wh[i]; }
    } else {
        size_t u = (size_t)(bid - BB * NCH) * 256 + tid;  // 8-elem unit, 2,097,152 total
        const float* g = &x[u * 8];
        float4 f0 = *reinterpret_cast<const float4*>(g);
        float4 f1 = *reinterpret_cast<const float4*>(g + 4);
        bf16x8 v;
        v[0] = (__bf16)f0.x; v[1] = (__bf16)f0.y; v[2] = (__bf16)f0.z; v[3] = (__bf16)f0.w;
        v[4] = (__bf16)f1.x; v[5] = (__bf16)f1.y; v[6] = (__bf16)f1.z; v[7] = (__bf16)f1.w;
        *reinterpret_cast<bf16x8*>(&xbf[u * 8]) = v;
    }
}

// ---------------- row totals + dinv (full-chip parallel) ----------------
__global__ __launch_bounds__(256) void rowstat_kernel(const int* __restrict__ chist, const float* __restrict__ wdeg,
                                                      int* __restrict__ rowtot, float* __restrict__ dinv) {
    int gid = blockIdx.x * 256 + threadIdx.x;   // 65536
    int b = gid >> 12, r = gid & (NN - 1);
    int tot = 0;
    float dsum = 1.0f;   // +1 self loop, always > 0
    #pragma unroll
    for (int c = 0; c < NCH; ++c) {
        size_t idx = ((size_t)b * NCH + c) * NN + r;
        tot += chist[idx];
        dsum += wdeg[idx];
    }
    rowtot[gid] = tot;
    dinv[gid] = rsqrtf(dsum);
}

// ---------------- per-batch exclusive scan of row totals (16 KB per block) ----------------
__global__ __launch_bounds__(1024) void scan3_kernel(const int* __restrict__ rowtot, int* __restrict__ roff) {
    int b = blockIdx.x, tid = threadIdx.x;
    int wid = tid >> 6, lane = tid & 63;
    __shared__ int wsum[16];
    __shared__ int wbase[16];
    __shared__ int gtot_s;
    int carry = 0;
    for (int g = 0; g < 4; ++g) {
        int r = g * 1024 + tid;
        int tot = rowtot[b * NN + r];
        int incl = tot;
        #pragma unroll
        for (int off = 1; off < 64; off <<= 1) {
            int t = __shfl_up(incl, off, 64);
            if (lane >= off) incl += t;
        }
        if (lane == 63) wsum[wid] = incl;
        __syncthreads();
        if (wid == 0) {
            int v = (lane < 16) ? wsum[lane] : 0;
            int winc = v;
            #pragma unroll
            for (int off = 1; off < 16; off <<= 1) {
                int t = __shfl_up(winc, off, 64);
                if (lane >= off) winc += t;
            }
            if (lane < 16) wbase[lane] = winc - v;
            if (lane == 15) gtot_s = winc;
        }
        __syncthreads();
        roff[b * NN + r] = carry + wbase[wid] + (incl - tot);
        carry += gtot_s;
        __syncthreads();
    }
}

// ---------------- per-chunk CSR bases (full-chip parallel) ----------------
__global__ __launch_bounds__(256) void chunkbase_kernel(const int* __restrict__ chist, const int* __restrict__ roff,
                                                        int* __restrict__ chunkbase) {
    int gid = blockIdx.x * 256 + threadIdx.x;
    int b = gid >> 12, r = gid & (NN - 1);
    int acc = roff[gid];
    #pragma unroll
    for (int c = 0; c < NCH; ++c) {
        size_t idx = ((size_t)b * NCH + c) * NN + r;
        int t = chist[idx];
        chunkbase[idx] = acc;
        acc += t;
    }
}

// ---------------- scatter into CSR slots — LDS atomics only, XCD-pinned ----------------
__global__ __launch_bounds__(256) void scatter2_kernel(const int* __restrict__ ei, const float* __restrict__ ew,
                                                       const float* __restrict__ dinv, const int* __restrict__ chunkbase,
                                                       int2* __restrict__ csr) {
    __shared__ int basebuf[NN];     // 16 KB
    __shared__ float dinvs[NN];     // 16 KB
    int bid = blockIdx.x;           // 256 blocks
    int xcd = bid & 7;
    int j = bid >> 3;
    int b = xcd * 2 + (j >> 4);
    int c = j & (NCH - 1);
    int tid = threadIdx.x;
    for (int i = tid; i < NN; i += 256) {
        basebuf[i] = chunkbase[((size_t)b * NCH + c) * NN + i];
        dinvs[i] = dinv[b * NN + i];
    }
    __syncthreads();
    const int* rows = ei + (size_t)b * 2 * EE + (size_t)c * CHE;
    const int* cols = rows + EE;
    const float* w = ew + (size_t)b * EE + (size_t)c * CHE;
    int2* cs = csr + (size_t)b * EE;
    #pragma unroll 4
    for (int jj = 0; jj < CHE / 256; ++jj) {
        int e = jj * 256 + tid;
        int row = rows[e];
        int col = cols[e];
        float nm = dinvs[row] * w[e] * dinvs[col];
        int pos = atomicAdd(&basebuf[row], 1);
        int2 pk; pk.x = col * (COUT * 2); pk.y = __float_as_int(nm);
        cs[pos] = pk;
    }
}

// ---------------- MFMA GEMM via global_load_lds: xw(bf16) = xbf @ wt^T ----------------
__global__ __launch_bounds__(256) void gemm_glds_kernel(const __bf16* __restrict__ xbf, const __bf16* __restrict__ wt,
                                                        __bf16* __restrict__ xw) {
    __shared__ __bf16 As[128 * 64];   // 16 KB, layout [r][k]
    __shared__ __bf16 Bs[128 * 64];   // 16 KB, layout [c][k]
    int tid = threadIdx.x;
    int lane = tid & 63;
    int wave = tid >> 6;
    int bx = blockIdx.x >> 1, by = blockIdx.x & 1;   // 1024 blocks -> (512, 2)
    int row0 = bx * 128, col0 = by * 128;
    int wr = wave >> 1, wc = wave & 1;
    int hi = lane >> 4, lo = lane & 15;
    int lr = lane >> 3, lk = (lane & 7) * 8;
    f32x4 acc[4][4] = {};

    for (int kk = 0; kk < CIN; kk += 64) {
        #pragma unroll
        for (int j = 0; j < 4; ++j) {
            int seg = j * 4 + wave;
            const __bf16* ga = &xbf[(size_t)(row0 + seg * 8 + lr) * CIN + kk + lk];
            const __bf16* gb = &wt [(size_t)(col0 + seg * 8 + lr) * CIN + kk + lk];
            GLDS16(ga, &As[seg * 512]);
            GLDS16(gb, &Bs[seg * 512]);
        }
        __syncthreads();
        #pragma unroll
        for (int ks = 0; ks < 2; ++ks) {
            bf16x8 a[4], b[4];
            #pragma unroll
            for (int m = 0; m < 4; ++m)
                a[m] = *reinterpret_cast<const bf16x8*>(&As[(wr * 64 + m * 16 + lo) * 64 + ks * 32 + 8 * hi]);
            #pragma unroll
            for (int n = 0; n < 4; ++n)
                b[n] = *reinterpret_cast<const bf16x8*>(&Bs[(wc * 64 + n * 16 + lo) * 64 + ks * 32 + 8 * hi]);
            #pragma unroll
            for (int m = 0; m < 4; ++m)
                #pragma unroll
                for (int n = 0; n < 4; ++n)
                    acc[m][n] = __builtin_amdgcn_mfma_f32_16x16x32_bf16(a[m], b[n], acc[m][n], 0, 0, 0);
        }
        __syncthreads();
    }
    #pragma unroll
    for (int m = 0; m < 4; ++m)
        #pragma unroll
        for (int n = 0; n < 4; ++n)
            #pragma unroll
            for (int r = 0; r < 4; ++r) {
                int row = row0 + wr * 64 + m * 16 + hi * 4 + r;
                int col = col0 + wc * 64 + n * 16 + lo;
                xw[(size_t)row * COUT + col] = (__bf16)acc[m][n][r];
            }
}

// ---------------- CSR aggregation v5: 2 INDEPENDENT rows/wave, scalar CSR loads, 8-deep ----------------
#define EDGE_FMA2(a01, a23, nmbits, raw) { \
    float nm_ = __int_as_float(nmbits); \
    f32x2 v01_, v23_; \
    v01_.x = __uint_as_float((raw).x << 16); \
    v01_.y = __uint_as_float((raw).x & 0xffff0000u); \
    v23_.x = __uint_as_float((raw).y << 16); \
    v23_.y = __uint_as_float((raw).y & 0xffff0000u); \
    a01 += nm_ * v01_; \
    a23 += nm_ * v23_; }

__global__ __launch_bounds__(256) void aggregate_kernel(const __bf16* __restrict__ xw, const float* __restrict__ dinv,
                                                        const int* __restrict__ roff, const int2* __restrict__ csr,
                                                        float* __restrict__ out) {
    int bid = blockIdx.x;            // 8192 blocks
    int xcd = bid & 7;
    int idx = bid >> 3;              // 0..1023
    int b = xcd * 2 + (idx >> 9);
    int rowoct = idx & 511;
    int wave = threadIdx.x >> 6;
    int lane = threadIdx.x & 63;
    int nA = rowoct * 8 + wave * 2;  // wave owns rows nA, nA+1
    int nB = nA + 1;

    const int* rb = roff + b * NN;
    int sA = __builtin_amdgcn_readfirstlane(rb[nA]);
    int sB = __builtin_amdgcn_readfirstlane(rb[nB]);
    int eB = __builtin_amdgcn_readfirstlane((nB == NN - 1) ? EE : rb[nB + 1]);
    int cntA = sB - sA, cntB = eB - sB;
    const int2* csA = csr + (size_t)b * EE + sA;
    const int2* csB = csr + (size_t)b * EE + sB;

    const char* xwb = (const char*)(xw + (size_t)b * NN * COUT) + lane * 8;

    f32x2 a01A, a23A, a01B, a23B;
    {   // self loops
        float diA = dinv[b * NN + nA], snA = diA * diA;
        uint2 sA_ = *reinterpret_cast<const uint2*>(xwb + (size_t)nA * (COUT * 2));
        a01A.x = snA * __uint_as_float(sA_.x << 16);
        a01A.y = snA * __uint_as_float(sA_.x & 0xffff0000u);
        a23A.x = snA * __uint_as_float(sA_.y << 16);
        a23A.y = snA * __uint_as_float(sA_.y & 0xffff0000u);
        float diB = dinv[b * NN + nB], snB = diB * diB;
        uint2 sB_ = *reinterpret_cast<const uint2*>(xwb + (size_t)nB * (COUT * 2));
        a01B.x = snB * __uint_as_float(sB_.x << 16);
        a01B.y = snB * __uint_as_float(sB_.x & 0xffff0000u);
        a23B.x = snB * __uint_as_float(sB_.y << 16);
        a23B.y = snB * __uint_as_float(sB_.y & 0xffff0000u);
    }

    int mA = cntA & ~7, mB = cntB & ~7;
    int mx = (mA > mB) ? mA : mB;
    for (int i = 0; i < mx; i += 8) {
        bool doA = i < mA, doB = i < mB;     // wave-uniform (scalar) conditions
        int2 qA[8], qB[8];
        if (doA) {
            #pragma unroll
            for (int u = 0; u < 8; ++u) qA[u] = csA[i + u];   // scalar s_loads
        }
        if (doB) {
            #pragma unroll
            for (int u = 0; u < 8; ++u) qB[u] = csB[i + u];
        }
        uint2 rA[8], rB[8];
        if (doA) {
            #pragma unroll
            for (int u = 0; u < 8; ++u) rA[u] = *reinterpret_cast<const uint2*>(xwb + qA[u].x);
        }
        if (doB) {
            #pragma unroll
            for (int u = 0; u < 8; ++u) rB[u] = *reinterpret_cast<const uint2*>(xwb + qB[u].x);
        }
        if (doA) {
            #pragma unroll
            for (int u = 0; u < 8; ++u) EDGE_FMA2(a01A, a23A, qA[u].y, rA[u]);
        }
        if (doB) {
            #pragma unroll
            for (int u = 0; u < 8; ++u) EDGE_FMA2(a01B, a23B, qB[u].y, rB[u]);
        }
    }
    if (mA < cntA) {   // clamped tail A (1..7 real edges; padding uses norm=0)
        #pragma unroll
        for (int u = 0; u < 8; ++u) {
            int j = mA + u;
            int jj = (j < cntA) ? j : (cntA - 1);
            int2 q = csA[jj];
            int nmb = (j < cntA) ? q.y : 0;
            uint2 raw = *reinterpret_cast<const uint2*>(xwb + q.x);
            EDGE_FMA2(a01A, a23A, nmb, raw);
        }
    }
    if (mB < cntB) {   // clamped tail B
        #pragma unroll
        for (int u = 0; u < 8; ++u) {
            int j = mB + u;
            int jj = (j < cntB) ? j : (cntB - 1);
            int2 q = csB[jj];
            int nmb = (j < cntB) ? q.y : 0;
            uint2 raw = *reinterpret_cast<const uint2*>(xwb + q.x);
            EDGE_FMA2(a01B, a23B, nmb, raw);
        }
    }

    float4 oA = make_float4(fmaxf(a01A.x, 0.f), fmaxf(a01A.y, 0.f), fmaxf(a23A.x, 0.f), fmaxf(a23A.y, 0.f));
    float4 oB = make_float4(fmaxf(a01B.x, 0.f), fmaxf(a01B.y, 0.f), fmaxf(a23B.x, 0.f), fmaxf(a23B.y, 0.f));
    *reinterpret_cast<float4*>(&out[((size_t)b * NN + nA) * COUT + 4 * lane]) = oA;
    *reinterpret_cast<float4*>(&out[((size_t)b * NN + nB) * COUT + 4 * lane]) = oB;
}

// ---------------- fallback (atomic) path ----------------
__global__ __launch_bounds__(256) void init_deg_kernel(float* __restrict__ deg, float v) {
    int i = blockIdx.x * 256 + threadIdx.x;
    if (i < BB * NN) deg[i] = v;
}

__global__ __launch_bounds__(256) void deg_only_kernel(const int* __restrict__ ei, const float* __restrict__ ew,
                                                       float* __restrict__ deg) {
    int idx = blockIdx.x * 256 + threadIdx.x;
    if (idx >= BB * EE) return;
    int b = idx / EE, e = idx - b * EE;
    atomicAdd(&deg[b * NN + ei[(size_t)b * 2 * EE + e]], ew[(size_t)b * EE + e]);
}

__global__ __launch_bounds__(256) void deginv_kernel(const float* __restrict__ deg, float* __restrict__ dinv) {
    int i = blockIdx.x * 256 + threadIdx.x;
    if (i < BB * NN) {
        float d = deg[i];
        dinv[i] = (d > 0.0f) ? rsqrtf(d) : 0.0f;
    }
}

__global__ __launch_bounds__(256) void gemm_f32src_kernel(const float* __restrict__ x, const __bf16* __restrict__ wt,
                                                          __bf16* __restrict__ xw) {
    __shared__ __bf16 As[128][64];
    __shared__ __bf16 Bs[128][64];
    int tid = threadIdx.x;
    int lane = tid & 63;
    int wave = tid >> 6;
    int row0 = blockIdx.x * 128;
    int col0 = blockIdx.y * 128;
    int wr = wave >> 1, wc = wave & 1;
    int hi = lane >> 4, lo = lane & 15;
    f32x4 acc[4][4] = {};
    for (int kk = 0; kk < CIN; kk += 64) {
        #pragma unroll
        for (int j = 0; j < 4; ++j) {
            int c = j * 256 + tid;
            int r = c >> 3, kq = c & 7;
            const float* g = &x[(size_t)(row0 + r) * CIN + kk + 8 * kq];
            float4 f0 = *reinterpret_cast<const float4*>(g);
            float4 f1 = *reinterpret_cast<const float4*>(g + 4);
            bf16x8 v;
            v[0] = (__bf16)f0.x; v[1] = (__bf16)f0.y; v[2] = (__bf16)f0.z; v[3] = (__bf16)f0.w;
            v[4] = (__bf16)f1.x; v[5] = (__bf16)f1.y; v[6] = (__bf16)f1.z; v[7] = (__bf16)f1.w;
            *reinterpret_cast<bf16x8*>(&As[r][8 * kq]) = v;
        }
        #pragma unroll
        for (int j = 0; j < 4; ++j) {
            int c = j * 256 + tid;
            int r = c >> 3, kq = c & 7;
            *reinterpret_cast<bf16x8*>(&Bs[r][8 * kq]) =
                *reinterpret_cast<const bf16x8*>(&wt[(size_t)(col0 + r) * CIN + kk + 8 * kq]);
        }
        __syncthreads();
        #pragma unroll
        for (int ks = 0; ks < 2; ++ks) {
            bf16x8 a[4], b[4];
            #pragma unroll
            for (int m = 0; m < 4; ++m)
                a[m] = *reinterpret_cast<const bf16x8*>(&As[wr * 64 + m * 16 + lo][ks * 32 + 8 * hi]);
            #pragma unroll
            for (int n = 0; n < 4; ++n)
                b[n] = *reinterpret_cast<const bf16x8*>(&Bs[wc * 64 + n * 16 + lo][ks * 32 + 8 * hi]);
            #pragma unroll
            for (int m = 0; m < 4; ++m)
                #pragma unroll
                for (int n = 0; n < 4; ++n)
                    acc[m][n] = __builtin_amdgcn_mfma_f32_16x16x32_bf16(a[m], b[n], acc[m][n], 0, 0, 0);
        }
        __syncthreads();
    }
    #pragma unroll
    for (int m = 0; m < 4; ++m)
        #pragma unroll
        for (int n = 0; n < 4; ++n)
            #pragma unroll
            for (int r = 0; r < 4; ++r) {
                int row = row0 + wr * 64 + m * 16 + hi * 4 + r;
                int col = col0 + wc * 64 + n * 16 + lo;
                xw[(size_t)row * COUT + col] = (__bf16)acc[m][n][r];
            }
}

__global__ __launch_bounds__(256) void self_kernel(const __bf16* __restrict__ xw, const float* __restrict__ dinv,
                                                   float* __restrict__ out) {
    int bn = blockIdx.x;
    int c = threadIdx.x;
    float di = dinv[bn];
    out[(size_t)bn * COUT + c] = di * di * (float)xw[(size_t)bn * COUT + c];
}

__global__ __launch_bounds__(256) void scatter_atomic_kernel(const int* __restrict__ ei, const float* __restrict__ ew,
                                                             const float* __restrict__ dinv,
                                                             const __bf16* __restrict__ xw, float* __restrict__ out) {
    int be = blockIdx.x;
    int b = be / EE, e = be - b * EE;
    int c = threadIdx.x;
    int row = ei[(size_t)b * 2 * EE + e];
    int col = ei[(size_t)b * 2 * EE + EE + e];
    float w = ew[(size_t)b * EE + e];
    float nm = dinv[b * NN + row] * w * dinv[b * NN + col];
    const __bf16* xwb = xw + (size_t)b * NN * COUT;
    atomicAdd(&out[((size_t)b * NN + row) * COUT + c], nm * (float)xwb[(size_t)col * COUT + c]);
}

__global__ __launch_bounds__(256) void relu_kernel(float* __restrict__ out) {
    size_t i = (size_t)blockIdx.x * 256 + threadIdx.x;
    out[i] = fmaxf(out[i], 0.0f);
}

extern "C" void kernel_launch(void* const* d_in, const int* in_sizes, int n_in,
                              void* d_out, int out_size, void* d_ws, size_t ws_size,
                              hipStream_t stream) {
    const float* x  = (const float*)d_in[0];
    const int*   ei = (const int*)d_in[1];
    const float* ew = (const float*)d_in[2];
    const float* Wm = (const float*)d_in[3];
    float* out = (float*)d_out;

    char* ws = (char*)d_ws;
    size_t off = 0;
    auto alloc = [&](size_t bytes) -> void* {
        void* p = ws + off;
        off += (bytes + 255) & ~(size_t)255;
        return p;
    };
    __bf16* xw        = (__bf16*)alloc((size_t)BB * NN * COUT * 2);   // 32 MB
    __bf16* xbf       = (__bf16*)alloc((size_t)BB * NN * CIN * 2);    // 32 MB
    int*    chist     = (int*)alloc((size_t)BB * NCH * NN * 4);       // 4 MB
    float*  wdeg      = (float*)alloc((size_t)BB * NCH * NN * 4);     // 4 MB
    int*    chunkbase = (int*)alloc((size_t)BB * NCH * NN * 4);       // 4 MB
    int*    roff      = (int*)alloc((size_t)BB * NN * 4);             // 256 KB
    float*  dinv      = (float*)alloc((size_t)BB * NN * 4);           // 256 KB
    __bf16* wt        = (__bf16*)alloc((size_t)CIN * COUT * 2);
    int2*   csr       = (int2*)xbf;        // alias: xbf dead after gemm, csr written after
    int*    rowtot    = (int*)chunkbase;   // alias: rowtot dead before chunkbase written
    float*  deg_fb    = (float*)chist;     // fallback-only alias
    bool use_csr = (ws_size >= off);

    cvt_wt_kernel<<<COUT, CIN, 0, stream>>>(Wm, wt);

    if (use_csr) {
        phaseA_kernel<<<BB * NCH + (BB * NN * CIN) / (256 * 8), 256, 0, stream>>>(x, xbf, ei, ew, chist, wdeg);
        rowstat_kernel<<<(BB * NN) / 256, 256, 0, stream>>>(chist, wdeg, rowtot, dinv);
        scan3_kernel<<<BB, 1024, 0, stream>>>(rowtot, roff);
        chunkbase_kernel<<<(BB * NN) / 256, 256, 0, stream>>>(chist, roff, chunkbase);
        gemm_glds_kernel<<<(BB * NN / 128) * (COUT / 128), 256, 0, stream>>>(xbf, wt, xw);
        scatter2_kernel<<<BB * NCH, 256, 0, stream>>>(ei, ew, dinv, chunkbase, csr);
        aggregate_kernel<<<BB * NN / 8, 256, 0, stream>>>(xw, dinv, roff, csr, out);
    } else {
        const int bnBlocks = (BB * NN) / 256;
        init_deg_kernel<<<bnBlocks, 256, 0, stream>>>(deg_fb, 1.0f);
        deg_only_kernel<<<(BB * EE) / 256, 256, 0, stream>>>(ei, ew, deg_fb);
        deginv_kernel<<<bnBlocks, 256, 0, stream>>>(deg_fb, dinv);
        dim3 ggrid((BB * NN) / 128, COUT / 128);
        gemm_f32src_kernel<<<ggrid, 256, 0, stream>>>(x, wt, xw);
        self_kernel<<<BB * NN, 256, 0, stream>>>(xw, dinv, out);
        scatter_atomic_kernel<<<BB * EE, 256, 0, stream>>>(ei, ew, dinv, xw, out);
        relu_kernel<<<(BB * NN * COUT) / 256, 256, 0, stream>>>(out);
    }
}

// Round 9
// 140.577 us; speedup vs baseline: 1.4835x; 1.1255x over previous
//
#include <hip/hip_runtime.h>
#include <cstdint>
#include <cstddef>

#define BB 16
#define NN 4096
#define EE 131072
#define CIN 256
#define COUT 256
#define NCH 16
#define CHE (EE / NCH)   // 8192 edges per chunk

typedef __attribute__((ext_vector_type(8))) __bf16 bf16x8;
typedef __attribute__((ext_vector_type(4))) float f32x4;
typedef __attribute__((ext_vector_type(2))) float f32x2;

#define GLDS16(g, l) __builtin_amdgcn_global_load_lds( \
    (const __attribute__((address_space(1))) uint32_t*)(g), \
    (__attribute__((address_space(3))) uint32_t*)(l), 16, 0, 0)

// ---------------- W transpose + bf16 cast: wt[n][k] = (bf16)W[k][n] ----------------
__global__ __launch_bounds__(256) void cvt_wt_kernel(const float* __restrict__ W, __bf16* __restrict__ wt) {
    int n = blockIdx.x;
    int k = threadIdx.x;
    wt[n * CIN + k] = (__bf16)W[(size_t)k * COUT + n];
}

// ---------------- phase A: hist (256 blocks) ∥ x->bf16 cvt (8192 blocks) ----------------
__global__ __launch_bounds__(256) void phaseA_kernel(const float* __restrict__ x, __bf16* __restrict__ xbf,
                                                     const int* __restrict__ ei, const float* __restrict__ ew,
                                                     int* __restrict__ chist, float* __restrict__ wdeg) {
    __shared__ int h[NN];       // 16 KB
    __shared__ float wh[NN];    // 16 KB
    int bid = blockIdx.x;
    int tid = threadIdx.x;
    if (bid < BB * NCH) {
        int b = bid >> 4, c = bid & (NCH - 1);
        for (int i = tid; i < NN; i += 256) { h[i] = 0; wh[i] = 0.f; }
        __syncthreads();
        const int* rows = ei + (size_t)b * 2 * EE + (size_t)c * CHE;
        const float* w = ew + (size_t)b * EE + (size_t)c * CHE;
        #pragma unroll 4
        for (int j = 0; j < CHE / 256; ++j) {
            int row = rows[j * 256 + tid];
            float wv = w[j * 256 + tid];
            atomicAdd(&h[row], 1);
            atomicAdd(&wh[row], wv);
        }
        __syncthreads();
        int* co = chist + ((size_t)b * NCH + c) * NN;
        float* wo = wdeg + ((size_t)b * NCH + c) * NN;
        for (int i = tid; i < NN; i += 256) { co[i] = h[i]; wo[i] = wh[i]; }
    } else {
        size_t u = (size_t)(bid - BB * NCH) * 256 + tid;  // 8-elem unit, 2,097,152 total
        const float* g = &x[u * 8];
        float4 f0 = *reinterpret_cast<const float4*>(g);
        float4 f1 = *reinterpret_cast<const float4*>(g + 4);
        bf16x8 v;
        v[0] = (__bf16)f0.x; v[1] = (__bf16)f0.y; v[2] = (__bf16)f0.z; v[3] = (__bf16)f0.w;
        v[4] = (__bf16)f1.x; v[5] = (__bf16)f1.y; v[6] = (__bf16)f1.z; v[7] = (__bf16)f1.w;
        *reinterpret_cast<bf16x8*>(&xbf[u * 8]) = v;
    }
}

// ---------------- fused: row totals + dinv + scan + per-chunk bases (16 blocks) ----------------
__global__ __launch_bounds__(1024) void scanfused_kernel(const int* __restrict__ chist, const float* __restrict__ wdeg,
                                                         int* __restrict__ chunkbase, int* __restrict__ roff,
                                                         float* __restrict__ dinv) {
    int b = blockIdx.x, tid = threadIdx.x;
    int wid = tid >> 6, lane = tid & 63;
    __shared__ int wsum[16];
    __shared__ int wbase[16];
    __shared__ int gtot_s;
    int carry = 0;
    for (int g = 0; g < 4; ++g) {
        int r = g * 1024 + tid;
        int cv[NCH];
        int tot = 0;
        float dsum = 1.0f;   // +1 self loop, always > 0
        #pragma unroll
        for (int c = 0; c < NCH; ++c) {
            size_t idx = ((size_t)b * NCH + c) * NN + r;
            cv[c] = chist[idx];
            tot += cv[c];
            dsum += wdeg[idx];
        }
        dinv[b * NN + r] = rsqrtf(dsum);
        int incl = tot;
        #pragma unroll
        for (int off = 1; off < 64; off <<= 1) {
            int t = __shfl_up(incl, off, 64);
            if (lane >= off) incl += t;
        }
        if (lane == 63) wsum[wid] = incl;
        __syncthreads();
        if (wid == 0) {
            int v = (lane < 16) ? wsum[lane] : 0;
            int winc = v;
            #pragma unroll
            for (int off = 1; off < 16; off <<= 1) {
                int t = __shfl_up(winc, off, 64);
                if (lane >= off) winc += t;
            }
            if (lane < 16) wbase[lane] = winc - v;
            if (lane == 15) gtot_s = winc;
        }
        __syncthreads();
        int excl = carry + wbase[wid] + (incl - tot);
        roff[b * NN + r] = excl;
        int acc = excl;
        #pragma unroll
        for (int c = 0; c < NCH; ++c) {
            chunkbase[((size_t)b * NCH + c) * NN + r] = acc;
            acc += cv[c];
        }
        carry += gtot_s;
        __syncthreads();
    }
}

// ---------------- scatter into CSR slots — LDS atomics only, XCD-pinned ----------------
__global__ __launch_bounds__(256) void scatter2_kernel(const int* __restrict__ ei, const float* __restrict__ ew,
                                                       const float* __restrict__ dinv, const int* __restrict__ chunkbase,
                                                       int2* __restrict__ csr) {
    __shared__ int basebuf[NN];     // 16 KB
    __shared__ float dinvs[NN];     // 16 KB
    int bid = blockIdx.x;           // 256 blocks
    int xcd = bid & 7;
    int j = bid >> 3;
    int b = xcd * 2 + (j >> 4);
    int c = j & (NCH - 1);
    int tid = threadIdx.x;
    for (int i = tid; i < NN; i += 256) {
        basebuf[i] = chunkbase[((size_t)b * NCH + c) * NN + i];
        dinvs[i] = dinv[b * NN + i];
    }
    __syncthreads();
    const int* rows = ei + (size_t)b * 2 * EE + (size_t)c * CHE;
    const int* cols = rows + EE;
    const float* w = ew + (size_t)b * EE + (size_t)c * CHE;
    int2* cs = csr + (size_t)b * EE;
    #pragma unroll 4
    for (int jj = 0; jj < CHE / 256; ++jj) {
        int e = jj * 256 + tid;
        int row = rows[e];
        int col = cols[e];
        float nm = dinvs[row] * w[e] * dinvs[col];
        int pos = atomicAdd(&basebuf[row], 1);
        int2 pk; pk.x = col * (COUT * 2); pk.y = __float_as_int(nm);
        cs[pos] = pk;
    }
}

// ---------------- MFMA GEMM via global_load_lds: xw(bf16) = xbf @ wt^T ----------------
__global__ __launch_bounds__(256) void gemm_glds_kernel(const __bf16* __restrict__ xbf, const __bf16* __restrict__ wt,
                                                        __bf16* __restrict__ xw) {
    __shared__ __bf16 As[128 * 64];   // 16 KB, layout [r][k]
    __shared__ __bf16 Bs[128 * 64];   // 16 KB, layout [c][k]
    int tid = threadIdx.x;
    int lane = tid & 63;
    int wave = tid >> 6;
    int bx = blockIdx.x >> 1, by = blockIdx.x & 1;   // 1024 blocks -> (512, 2)
    int row0 = bx * 128, col0 = by * 128;
    int wr = wave >> 1, wc = wave & 1;
    int hi = lane >> 4, lo = lane & 15;
    int lr = lane >> 3, lk = (lane & 7) * 8;
    f32x4 acc[4][4] = {};

    for (int kk = 0; kk < CIN; kk += 64) {
        #pragma unroll
        for (int j = 0; j < 4; ++j) {
            int seg = j * 4 + wave;
            const __bf16* ga = &xbf[(size_t)(row0 + seg * 8 + lr) * CIN + kk + lk];
            const __bf16* gb = &wt [(size_t)(col0 + seg * 8 + lr) * CIN + kk + lk];
            GLDS16(ga, &As[seg * 512]);
            GLDS16(gb, &Bs[seg * 512]);
        }
        __syncthreads();
        #pragma unroll
        for (int ks = 0; ks < 2; ++ks) {
            bf16x8 a[4], b[4];
            #pragma unroll
            for (int m = 0; m < 4; ++m)
                a[m] = *reinterpret_cast<const bf16x8*>(&As[(wr * 64 + m * 16 + lo) * 64 + ks * 32 + 8 * hi]);
            #pragma unroll
            for (int n = 0; n < 4; ++n)
                b[n] = *reinterpret_cast<const bf16x8*>(&Bs[(wc * 64 + n * 16 + lo) * 64 + ks * 32 + 8 * hi]);
            #pragma unroll
            for (int m = 0; m < 4; ++m)
                #pragma unroll
                for (int n = 0; n < 4; ++n)
                    acc[m][n] = __builtin_amdgcn_mfma_f32_16x16x32_bf16(a[m], b[n], acc[m][n], 0, 0, 0);
        }
        __syncthreads();
    }
    #pragma unroll
    for (int m = 0; m < 4; ++m)
        #pragma unroll
        for (int n = 0; n < 4; ++n)
            #pragma unroll
            for (int r = 0; r < 4; ++r) {
                int row = row0 + wr * 64 + m * 16 + hi * 4 + r;
                int col = col0 + wc * 64 + n * 16 + lo;
                xw[(size_t)row * COUT + col] = (__bf16)acc[m][n][r];
            }
}

// ---------------- CSR aggregation v6: 2 edges per gather (dwordx4/lane), scalar CSR ----------------
// Lane layout: lanes 0-31 take even edge of each pair, lanes 32-63 odd edge.
// Each lane gathers 16 B = 8 channels at (lane&31)*16 within the source row.
#define BFLO(u) __uint_as_float((u) << 16)
#define BFHI(u) __uint_as_float((u) & 0xffff0000u)
#define ACC8(nm, raw) { \
    acc0.x += (nm) * BFLO((raw).x); acc0.y += (nm) * BFHI((raw).x); \
    acc1.x += (nm) * BFLO((raw).y); acc1.y += (nm) * BFHI((raw).y); \
    acc2.x += (nm) * BFLO((raw).z); acc2.y += (nm) * BFHI((raw).z); \
    acc3.x += (nm) * BFLO((raw).w); acc3.y += (nm) * BFHI((raw).w); }

__global__ __launch_bounds__(256) void aggregate_kernel(const __bf16* __restrict__ xw, const float* __restrict__ dinv,
                                                        const int* __restrict__ roff, const int2* __restrict__ csr,
                                                        float* __restrict__ out) {
    int bid = blockIdx.x;            // 16384 blocks
    int xcd = bid & 7;
    int idx = bid >> 3;              // 0..2047
    int b = xcd * 2 + (idx >> 10);
    int rowblk = idx & 1023;
    int wave = threadIdx.x >> 6;
    int lane = threadIdx.x & 63;
    int n = rowblk * 4 + wave;       // 1 row per wave
    bool hiHalf = lane >= 32;
    int sub = lane & 31;             // 16B-granule index within row

    const int* rb = roff + b * NN;
    int s = __builtin_amdgcn_readfirstlane(rb[n]);
    int eRaw = (n == NN - 1) ? EE : rb[n + 1];
    int e = __builtin_amdgcn_readfirstlane(eRaw);
    int cnt = e - s;
    const int2* cs = csr + (size_t)b * EE + s;

    const char* xwb = (const char*)(xw + (size_t)b * NN * COUT) + sub * 16;
    f32x2 acc0 = {0.f, 0.f}, acc1 = {0.f, 0.f}, acc2 = {0.f, 0.f}, acc3 = {0.f, 0.f};

    {   // self loop (low half only; high half gets nm=0 but reads same row — harmless)
        float di = dinv[b * NN + n];
        float sn = hiHalf ? 0.f : di * di;
        uint4 raw = *reinterpret_cast<const uint4*>(xwb + (size_t)n * (COUT * 2));
        ACC8(sn, raw);
    }

    int m = cnt & ~7;
    int i = 0;
    for (; i < m; i += 8) {
        int2 q[8];
        #pragma unroll
        for (int u = 0; u < 8; ++u) q[u] = cs[i + u];   // wave-uniform -> scalar s_loads
        #pragma unroll
        for (int u = 0; u < 4; ++u) {
            int offx = hiHalf ? q[2 * u + 1].x : q[2 * u].x;
            float nm = __int_as_float(hiHalf ? q[2 * u + 1].y : q[2 * u].y);
            uint4 raw = *reinterpret_cast<const uint4*>(xwb + offx);
            ACC8(nm, raw);
        }
    }
    if (i < cnt) {   // 1..7 remaining; pad pairs with nm=0 (clamped index)
        #pragma unroll
        for (int u = 0; u < 4; ++u) {
            int j0 = i + 2 * u, j1 = j0 + 1;
            int jc0 = (j0 < cnt) ? j0 : cnt - 1;
            int jc1 = (j1 < cnt) ? j1 : cnt - 1;
            int2 q0 = cs[jc0];
            int2 q1 = cs[jc1];
            int offx = hiHalf ? q1.x : q0.x;
            float nm0 = (j0 < cnt) ? __int_as_float(q0.y) : 0.f;
            float nm1 = (j1 < cnt) ? __int_as_float(q1.y) : 0.f;
            float nm = hiHalf ? nm1 : nm0;
            uint4 raw = *reinterpret_cast<const uint4*>(xwb + offx);
            ACC8(nm, raw);
        }
    }

    // cross-half combine: partner lane = lane ^ 32
    acc0.x += __shfl(acc0.x, lane ^ 32, 64); acc0.y += __shfl(acc0.y, lane ^ 32, 64);
    acc1.x += __shfl(acc1.x, lane ^ 32, 64); acc1.y += __shfl(acc1.y, lane ^ 32, 64);
    acc2.x += __shfl(acc2.x, lane ^ 32, 64); acc2.y += __shfl(acc2.y, lane ^ 32, 64);
    acc3.x += __shfl(acc3.x, lane ^ 32, 64); acc3.y += __shfl(acc3.y, lane ^ 32, 64);

    // store: low half writes ch[8*sub..8*sub+4), high half ch[8*sub+4..8*sub+8)
    float4 o = hiHalf
        ? make_float4(fmaxf(acc2.x, 0.f), fmaxf(acc2.y, 0.f), fmaxf(acc3.x, 0.f), fmaxf(acc3.y, 0.f))
        : make_float4(fmaxf(acc0.x, 0.f), fmaxf(acc0.y, 0.f), fmaxf(acc1.x, 0.f), fmaxf(acc1.y, 0.f));
    float* orow = out + ((size_t)b * NN + n) * COUT + sub * 8 + (hiHalf ? 4 : 0);
    *reinterpret_cast<float4*>(orow) = o;
}

// ---------------- fallback (atomic) path ----------------
__global__ __launch_bounds__(256) void init_deg_kernel(float* __restrict__ deg, float v) {
    int i = blockIdx.x * 256 + threadIdx.x;
    if (i < BB * NN) deg[i] = v;
}

__global__ __launch_bounds__(256) void deg_only_kernel(const int* __restrict__ ei, const float* __restrict__ ew,
                                                       float* __restrict__ deg) {
    int idx = blockIdx.x * 256 + threadIdx.x;
    if (idx >= BB * EE) return;
    int b = idx / EE, e = idx - b * EE;
    atomicAdd(&deg[b * NN + ei[(size_t)b * 2 * EE + e]], ew[(size_t)b * EE + e]);
}

__global__ __launch_bounds__(256) void deginv_kernel(const float* __restrict__ deg, float* __restrict__ dinv) {
    int i = blockIdx.x * 256 + threadIdx.x;
    if (i < BB * NN) {
        float d = deg[i];
        dinv[i] = (d > 0.0f) ? rsqrtf(d) : 0.0f;
    }
}

__global__ __launch_bounds__(256) void gemm_f32src_kernel(const float* __restrict__ x, const __bf16* __restrict__ wt,
                                                          __bf16* __restrict__ xw) {
    __shared__ __bf16 As[128][64];
    __shared__ __bf16 Bs[128][64];
    int tid = threadIdx.x;
    int lane = tid & 63;
    int wave = tid >> 6;
    int row0 = blockIdx.x * 128;
    int col0 = blockIdx.y * 128;
    int wr = wave >> 1, wc = wave & 1;
    int hi = lane >> 4, lo = lane & 15;
    f32x4 acc[4][4] = {};
    for (int kk = 0; kk < CIN; kk += 64) {
        #pragma unroll
        for (int j = 0; j < 4; ++j) {
            int c = j * 256 + tid;
            int r = c >> 3, kq = c & 7;
            const float* g = &x[(size_t)(row0 + r) * CIN + kk + 8 * kq];
            float4 f0 = *reinterpret_cast<const float4*>(g);
            float4 f1 = *reinterpret_cast<const float4*>(g + 4);
            bf16x8 v;
            v[0] = (__bf16)f0.x; v[1] = (__bf16)f0.y; v[2] = (__bf16)f0.z; v[3] = (__bf16)f0.w;
            v[4] = (__bf16)f1.x; v[5] = (__bf16)f1.y; v[6] = (__bf16)f1.z; v[7] = (__bf16)f1.w;
            *reinterpret_cast<bf16x8*>(&As[r][8 * kq]) = v;
        }
        #pragma unroll
        for (int j = 0; j < 4; ++j) {
            int c = j * 256 + tid;
            int r = c >> 3, kq = c & 7;
            *reinterpret_cast<bf16x8*>(&Bs[r][8 * kq]) =
                *reinterpret_cast<const bf16x8*>(&wt[(size_t)(col0 + r) * CIN + kk + 8 * kq]);
        }
        __syncthreads();
        #pragma unroll
        for (int ks = 0; ks < 2; ++ks) {
            bf16x8 a[4], b[4];
            #pragma unroll
            for (int m = 0; m < 4; ++m)
                a[m] = *reinterpret_cast<const bf16x8*>(&As[wr * 64 + m * 16 + lo][ks * 32 + 8 * hi]);
            #pragma unroll
            for (int n = 0; n < 4; ++n)
                b[n] = *reinterpret_cast<const bf16x8*>(&Bs[wc * 64 + n * 16 + lo][ks * 32 + 8 * hi]);
            #pragma unroll
            for (int m = 0; m < 4; ++m)
                #pragma unroll
                for (int n = 0; n < 4; ++n)
                    acc[m][n] = __builtin_amdgcn_mfma_f32_16x16x32_bf16(a[m], b[n], acc[m][n], 0, 0, 0);
        }
        __syncthreads();
    }
    #pragma unroll
    for (int m = 0; m < 4; ++m)
        #pragma unroll
        for (int n = 0; n < 4; ++n)
            #pragma unroll
            for (int r = 0; r < 4; ++r) {
                int row = row0 + wr * 64 + m * 16 + hi * 4 + r;
                int col = col0 + wc * 64 + n * 16 + lo;
                xw[(size_t)row * COUT + col] = (__bf16)acc[m][n][r];
            }
}

__global__ __launch_bounds__(256) void self_kernel(const __bf16* __restrict__ xw, const float* __restrict__ dinv,
                                                   float* __restrict__ out) {
    int bn = blockIdx.x;
    int c = threadIdx.x;
    float di = dinv[bn];
    out[(size_t)bn * COUT + c] = di * di * (float)xw[(size_t)bn * COUT + c];
}

__global__ __launch_bounds__(256) void scatter_atomic_kernel(const int* __restrict__ ei, const float* __restrict__ ew,
                                                             const float* __restrict__ dinv,
                                                             const __bf16* __restrict__ xw, float* __restrict__ out) {
    int be = blockIdx.x;
    int b = be / EE, e = be - b * EE;
    int c = threadIdx.x;
    int row = ei[(size_t)b * 2 * EE + e];
    int col = ei[(size_t)b * 2 * EE + EE + e];
    float w = ew[(size_t)b * EE + e];
    float nm = dinv[b * NN + row] * w * dinv[b * NN + col];
    const __bf16* xwb = xw + (size_t)b * NN * COUT;
    atomicAdd(&out[((size_t)b * NN + row) * COUT + c], nm * (float)xwb[(size_t)col * COUT + c]);
}

__global__ __launch_bounds__(256) void relu_kernel(float* __restrict__ out) {
    size_t i = (size_t)blockIdx.x * 256 + threadIdx.x;
    out[i] = fmaxf(out[i], 0.0f);
}

extern "C" void kernel_launch(void* const* d_in, const int* in_sizes, int n_in,
                              void* d_out, int out_size, void* d_ws, size_t ws_size,
                              hipStream_t stream) {
    const float* x  = (const float*)d_in[0];
    const int*   ei = (const int*)d_in[1];
    const float* ew = (const float*)d_in[2];
    const float* Wm = (const float*)d_in[3];
    float* out = (float*)d_out;

    char* ws = (char*)d_ws;
    size_t off = 0;
    auto alloc = [&](size_t bytes) -> void* {
        void* p = ws + off;
        off += (bytes + 255) & ~(size_t)255;
        return p;
    };
    __bf16* xw        = (__bf16*)alloc((size_t)BB * NN * COUT * 2);   // 32 MB
    __bf16* xbf       = (__bf16*)alloc((size_t)BB * NN * CIN * 2);    // 32 MB
    int*    chist     = (int*)alloc((size_t)BB * NCH * NN * 4);       // 4 MB
    float*  wdeg      = (float*)alloc((size_t)BB * NCH * NN * 4);     // 4 MB
    int*    chunkbase = (int*)alloc((size_t)BB * NCH * NN * 4);       // 4 MB
    int*    roff      = (int*)alloc((size_t)BB * NN * 4);             // 256 KB
    float*  dinv      = (float*)alloc((size_t)BB * NN * 4);           // 256 KB
    __bf16* wt        = (__bf16*)alloc((size_t)CIN * COUT * 2);
    int2*   csr       = (int2*)xbf;        // alias: xbf dead after gemm, csr written after
    float*  deg_fb    = (float*)chist;     // fallback-only alias
    bool use_csr = (ws_size >= off);

    cvt_wt_kernel<<<COUT, CIN, 0, stream>>>(Wm, wt);

    if (use_csr) {
        phaseA_kernel<<<BB * NCH + (BB * NN * CIN) / (256 * 8), 256, 0, stream>>>(x, xbf, ei, ew, chist, wdeg);
        scanfused_kernel<<<BB, 1024, 0, stream>>>(chist, wdeg, chunkbase, roff, dinv);
        gemm_glds_kernel<<<(BB * NN / 128) * (COUT / 128), 256, 0, stream>>>(xbf, wt, xw);
        scatter2_kernel<<<BB * NCH, 256, 0, stream>>>(ei, ew, dinv, chunkbase, csr);
        aggregate_kernel<<<BB * NN / 4, 256, 0, stream>>>(xw, dinv, roff, csr, out);
    } else {
        const int bnBlocks = (BB * NN) / 256;
        init_deg_kernel<<<bnBlocks, 256, 0, stream>>>(deg_fb, 1.0f);
        deg_only_kernel<<<(BB * EE) / 256, 256, 0, stream>>>(ei, ew, deg_fb);
        deginv_kernel<<<bnBlocks, 256, 0, stream>>>(deg_fb, dinv);
        dim3 ggrid((BB * NN) / 128, COUT / 128);
        gemm_f32src_kernel<<<ggrid, 256, 0, stream>>>(x, wt, xw);
        self_kernel<<<BB * NN, 256, 0, stream>>>(xw, dinv, out);
        scatter_atomic_kernel<<<BB * EE, 256, 0, stream>>>(ei, ew, dinv, xw, out);
        relu_kernel<<<(BB * NN * COUT) / 256, 256, 0, stream>>>(out);
    }
}

// Round 11
// 135.586 us; speedup vs baseline: 1.5381x; 1.0368x over previous
//
#include <hip/hip_runtime.h>
#include <cstdint>
#include <cstddef>

#define BB 16
#define NN 4096
#define EE 131072
#define CIN 256
#define COUT 256
#define NCH 16
#define CHE (EE / NCH)   // 8192 edges per chunk

typedef __attribute__((ext_vector_type(8))) _Float16 h16x8;
typedef __attribute__((ext_vector_type(4))) float f32x4;

#define GLDS16(g, l) __builtin_amdgcn_global_load_lds( \
    (const __attribute__((address_space(1))) uint32_t*)(g), \
    (__attribute__((address_space(3))) uint32_t*)(l), 16, 0, 0)

// ---------------- phase A: hist (blocks 0..255) ∥ x->fp16 (256..8447) ∥ W^T->fp16 (8448..8703) ----------------
__global__ __launch_bounds__(256) void phaseA_kernel(const float* __restrict__ x, _Float16* __restrict__ xh,
                                                     const float* __restrict__ W, _Float16* __restrict__ wt,
                                                     const int* __restrict__ ei, const float* __restrict__ ew,
                                                     int* __restrict__ chist, float* __restrict__ wdeg) {
    __shared__ int h[NN];       // 16 KB
    __shared__ float wh[NN];    // 16 KB
    int bid = blockIdx.x;
    int tid = threadIdx.x;
    if (bid < BB * NCH) {
        int b = bid >> 4, c = bid & (NCH - 1);
        for (int i = tid; i < NN; i += 256) { h[i] = 0; wh[i] = 0.f; }
        __syncthreads();
        const int* rows = ei + (size_t)b * 2 * EE + (size_t)c * CHE;
        const float* w = ew + (size_t)b * EE + (size_t)c * CHE;
        #pragma unroll 4
        for (int j = 0; j < CHE / 256; ++j) {
            int row = rows[j * 256 + tid];
            float wv = w[j * 256 + tid];
            atomicAdd(&h[row], 1);
            atomicAdd(&wh[row], wv);
        }
        __syncthreads();
        int* co = chist + ((size_t)b * NCH + c) * NN;
        float* wo = wdeg + ((size_t)b * NCH + c) * NN;
        for (int i = tid; i < NN; i += 256) { co[i] = h[i]; wo[i] = wh[i]; }
    } else if (bid < BB * NCH + (BB * NN * CIN) / (256 * 8)) {
        size_t u = (size_t)(bid - BB * NCH) * 256 + tid;  // 8-elem unit
        const float* g = &x[u * 8];
        float4 f0 = *reinterpret_cast<const float4*>(g);
        float4 f1 = *reinterpret_cast<const float4*>(g + 4);
        h16x8 v;
        v[0] = (_Float16)f0.x; v[1] = (_Float16)f0.y; v[2] = (_Float16)f0.z; v[3] = (_Float16)f0.w;
        v[4] = (_Float16)f1.x; v[5] = (_Float16)f1.y; v[6] = (_Float16)f1.z; v[7] = (_Float16)f1.w;
        *reinterpret_cast<h16x8*>(&xh[u * 8]) = v;
    } else {
        int n = bid - (BB * NCH + (BB * NN * CIN) / (256 * 8));   // 0..255
        int k = tid;
        wt[n * CIN + k] = (_Float16)W[(size_t)k * COUT + n];
    }
}

// ---------------- fused: row totals + dinv + scan + per-chunk bases (16 blocks) ----------------
__global__ __launch_bounds__(1024) void scanfused_kernel(const int* __restrict__ chist, const float* __restrict__ wdeg,
                                                         int* __restrict__ chunkbase, int* __restrict__ roff,
                                                         float* __restrict__ dinv) {
    int b = blockIdx.x, tid = threadIdx.x;
    int wid = tid >> 6, lane = tid & 63;
    __shared__ int wsum[16];
    __shared__ int wbase[16];
    __shared__ int gtot_s;
    int carry = 0;
    for (int g = 0; g < 4; ++g) {
        int r = g * 1024 + tid;
        int cv[NCH];
        int tot = 0;
        float dsum = 1.0f;   // +1 self loop, always > 0
        #pragma unroll
        for (int c = 0; c < NCH; ++c) {
            size_t idx = ((size_t)b * NCH + c) * NN + r;
            cv[c] = chist[idx];
            tot += cv[c];
            dsum += wdeg[idx];
        }
        dinv[b * NN + r] = rsqrtf(dsum);
        int incl = tot;
        #pragma unroll
        for (int off = 1; off < 64; off <<= 1) {
            int t = __shfl_up(incl, off, 64);
            if (lane >= off) incl += t;
        }
        if (lane == 63) wsum[wid] = incl;
        __syncthreads();
        if (wid == 0) {
            int v = (lane < 16) ? wsum[lane] : 0;
            int winc = v;
            #pragma unroll
            for (int off = 1; off < 16; off <<= 1) {
                int t = __shfl_up(winc, off, 64);
                if (lane >= off) winc += t;
            }
            if (lane < 16) wbase[lane] = winc - v;
            if (lane == 15) gtot_s = winc;
        }
        __syncthreads();
        int excl = carry + wbase[wid] + (incl - tot);
        roff[b * NN + r] = excl;
        int acc = excl;
        #pragma unroll
        for (int c = 0; c < NCH; ++c) {
            chunkbase[((size_t)b * NCH + c) * NN + r] = acc;
            acc += cv[c];
        }
        carry += gtot_s;
        __syncthreads();
    }
}

// ---------------- MFMA GEMM via global_load_lds: xw(fp16) = xh @ wt^T ----------------
__global__ __launch_bounds__(256) void gemm_glds_kernel(const _Float16* __restrict__ xh, const _Float16* __restrict__ wt,
                                                        _Float16* __restrict__ xw) {
    __shared__ _Float16 As[128 * 64];   // 16 KB, [r][k]
    __shared__ _Float16 Bs[128 * 64];   // 16 KB, [c][k]
    int tid = threadIdx.x;
    int lane = tid & 63;
    int wave = tid >> 6;
    int bx = blockIdx.x >> 1, by = blockIdx.x & 1;   // 1024 blocks -> (512, 2)
    int row0 = bx * 128, col0 = by * 128;
    int wr = wave >> 1, wc = wave & 1;
    int hi = lane >> 4, lo = lane & 15;
    int lr = lane >> 3, lk = (lane & 7) * 8;
    f32x4 acc[4][4] = {};

    for (int kk = 0; kk < CIN; kk += 64) {
        #pragma unroll
        for (int j = 0; j < 4; ++j) {
            int seg = j * 4 + wave;
            const _Float16* ga = &xh[(size_t)(row0 + seg * 8 + lr) * CIN + kk + lk];
            const _Float16* gb = &wt [(size_t)(col0 + seg * 8 + lr) * CIN + kk + lk];
            GLDS16(ga, &As[seg * 512]);
            GLDS16(gb, &Bs[seg * 512]);
        }
        __syncthreads();
        #pragma unroll
        for (int ks = 0; ks < 2; ++ks) {
            h16x8 a[4], b[4];
            #pragma unroll
            for (int m = 0; m < 4; ++m)
                a[m] = *reinterpret_cast<const h16x8*>(&As[(wr * 64 + m * 16 + lo) * 64 + ks * 32 + 8 * hi]);
            #pragma unroll
            for (int n = 0; n < 4; ++n)
                b[n] = *reinterpret_cast<const h16x8*>(&Bs[(wc * 64 + n * 16 + lo) * 64 + ks * 32 + 8 * hi]);
            #pragma unroll
            for (int m = 0; m < 4; ++m)
                #pragma unroll
                for (int n = 0; n < 4; ++n)
                    acc[m][n] = __builtin_amdgcn_mfma_f32_16x16x32_f16(a[m], b[n], acc[m][n], 0, 0, 0);
        }
        __syncthreads();
    }
    #pragma unroll
    for (int m = 0; m < 4; ++m)
        #pragma unroll
        for (int n = 0; n < 4; ++n)
            #pragma unroll
            for (int r = 0; r < 4; ++r) {
                int row = row0 + wr * 64 + m * 16 + hi * 4 + r;
                int col = col0 + wc * 64 + n * 16 + lo;
                xw[(size_t)row * COUT + col] = (_Float16)acc[m][n][r];
            }
}

// ---------------- scatter into CSR slots — LDS atomics only, XCD-pinned ----------------
// csr entry: {x = col*512 (byte offset into fp16 xw slab), y = norm bits}
// NOTE: csr aliases xh -> this kernel MUST run after gemm_glds_kernel completes (separate dispatch).
__global__ __launch_bounds__(256) void scatter2_kernel(const int* __restrict__ ei, const float* __restrict__ ew,
                                                       const float* __restrict__ dinv, const int* __restrict__ chunkbase,
                                                       int2* __restrict__ csr) {
    __shared__ int basebuf[NN];     // 16 KB
    __shared__ float dinvs[NN];     // 16 KB
    int bid = blockIdx.x;           // 256 blocks
    int xcd = bid & 7;
    int j = bid >> 3;
    int b = xcd * 2 + (j >> 4);
    int c = j & (NCH - 1);
    int tid = threadIdx.x;
    for (int i = tid; i < NN; i += 256) {
        basebuf[i] = chunkbase[((size_t)b * NCH + c) * NN + i];
        dinvs[i] = dinv[b * NN + i];
    }
    __syncthreads();
    const int* rows = ei + (size_t)b * 2 * EE + (size_t)c * CHE;
    const int* cols = rows + EE;
    const float* w = ew + (size_t)b * EE + (size_t)c * CHE;
    int2* cs = csr + (size_t)b * EE;
    #pragma unroll 4
    for (int jj = 0; jj < CHE / 256; ++jj) {
        int e = jj * 256 + tid;
        int row = rows[e];
        int col = cols[e];
        float nm = dinvs[row] * w[e] * dinvs[col];
        int pos = atomicAdd(&basebuf[row], 1);
        int2 pk; pk.x = col * (COUT * 2); pk.y = __float_as_int(nm);
        cs[pos] = pk;
    }
}

// ---------------- CSR aggregation v7: fp16 gathers (fma_mix), 2 edges/instr, scalar CSR ----------------
#define ACCH(nm, r) { \
    a0 += (nm) * (float)(r)[0]; a1 += (nm) * (float)(r)[1]; \
    a2 += (nm) * (float)(r)[2]; a3 += (nm) * (float)(r)[3]; \
    a4 += (nm) * (float)(r)[4]; a5 += (nm) * (float)(r)[5]; \
    a6 += (nm) * (float)(r)[6]; a7 += (nm) * (float)(r)[7]; }

__global__ __launch_bounds__(256) void aggregate_kernel(const _Float16* __restrict__ xw, const float* __restrict__ dinv,
                                                        const int* __restrict__ roff, const int2* __restrict__ csr,
                                                        float* __restrict__ out) {
    int bid = blockIdx.x;            // 16384 blocks
    int xcd = bid & 7;
    int idx = bid >> 3;              // 0..2047
    int b = xcd * 2 + (idx >> 10);
    int rowblk = idx & 1023;
    int wave = threadIdx.x >> 6;
    int lane = threadIdx.x & 63;
    int n = rowblk * 4 + wave;       // 1 row per wave
    bool hiHalf = lane >= 32;
    int sub = lane & 31;             // 16B-granule index within row
    int lanebyte = sub * 16;

    const int* rb = roff + b * NN;
    int s = __builtin_amdgcn_readfirstlane(rb[n]);
    int eRaw = (n == NN - 1) ? EE : rb[n + 1];
    int e = __builtin_amdgcn_readfirstlane(eRaw);
    int cnt = e - s;
    const int2* cs = csr + (size_t)b * EE + s;

    const char* xwbase = (const char*)(xw + (size_t)b * NN * COUT);   // wave-uniform base
    float a0 = 0.f, a1 = 0.f, a2 = 0.f, a3 = 0.f, a4 = 0.f, a5 = 0.f, a6 = 0.f, a7 = 0.f;

    {   // self loop (low half applies; high half nm=0, read harmless)
        float di = dinv[b * NN + n];
        float sn = hiHalf ? 0.f : di * di;
        h16x8 r = *reinterpret_cast<const h16x8*>(xwbase + (size_t)n * (COUT * 2) + lanebyte);
        ACCH(sn, r);
    }

    int m = cnt & ~7;
    int i = 0;
    for (; i < m; i += 8) {
        int2 q[8];
        #pragma unroll
        for (int u = 0; u < 8; ++u) q[u] = cs[i + u];   // wave-uniform -> scalar s_loads
        #pragma unroll
        for (int u = 0; u < 4; ++u) {
            int offx = (hiHalf ? q[2 * u + 1].x : q[2 * u].x) + lanebyte;
            float nm = __int_as_float(hiHalf ? q[2 * u + 1].y : q[2 * u].y);
            h16x8 r = *reinterpret_cast<const h16x8*>(xwbase + (uint32_t)offx);
            ACCH(nm, r);
        }
    }
    if (i < cnt) {   // 1..7 remaining; pad with nm=0 (clamped index)
        #pragma unroll
        for (int u = 0; u < 4; ++u) {
            int j0 = i + 2 * u, j1 = j0 + 1;
            int jc0 = (j0 < cnt) ? j0 : cnt - 1;
            int jc1 = (j1 < cnt) ? j1 : cnt - 1;
            int2 q0 = cs[jc0];
            int2 q1 = cs[jc1];
            int offx = (hiHalf ? q1.x : q0.x) + lanebyte;
            float nm0 = (j0 < cnt) ? __int_as_float(q0.y) : 0.f;
            float nm1 = (j1 < cnt) ? __int_as_float(q1.y) : 0.f;
            float nm = hiHalf ? nm1 : nm0;
            h16x8 r = *reinterpret_cast<const h16x8*>(xwbase + (uint32_t)offx);
            ACCH(nm, r);
        }
    }

    // cross-half combine: partner lane = lane ^ 32
    a0 += __shfl(a0, lane ^ 32, 64); a1 += __shfl(a1, lane ^ 32, 64);
    a2 += __shfl(a2, lane ^ 32, 64); a3 += __shfl(a3, lane ^ 32, 64);
    a4 += __shfl(a4, lane ^ 32, 64); a5 += __shfl(a5, lane ^ 32, 64);
    a6 += __shfl(a6, lane ^ 32, 64); a7 += __shfl(a7, lane ^ 32, 64);

    float4 o = hiHalf
        ? make_float4(fmaxf(a4, 0.f), fmaxf(a5, 0.f), fmaxf(a6, 0.f), fmaxf(a7, 0.f))
        : make_float4(fmaxf(a0, 0.f), fmaxf(a1, 0.f), fmaxf(a2, 0.f), fmaxf(a3, 0.f));
    float* orow = out + ((size_t)b * NN + n) * COUT + sub * 8 + (hiHalf ? 4 : 0);
    *reinterpret_cast<float4*>(orow) = o;
}

// ---------------- fallback (atomic) path ----------------
__global__ __launch_bounds__(256) void cvt_wt_kernel(const float* __restrict__ W, _Float16* __restrict__ wt) {
    int n = blockIdx.x;
    int k = threadIdx.x;
    wt[n * CIN + k] = (_Float16)W[(size_t)k * COUT + n];
}

__global__ __launch_bounds__(256) void init_deg_kernel(float* __restrict__ deg, float v) {
    int i = blockIdx.x * 256 + threadIdx.x;
    if (i < BB * NN) deg[i] = v;
}

__global__ __launch_bounds__(256) void deg_only_kernel(const int* __restrict__ ei, const float* __restrict__ ew,
                                                       float* __restrict__ deg) {
    int idx = blockIdx.x * 256 + threadIdx.x;
    if (idx >= BB * EE) return;
    int b = idx / EE, e = idx - b * EE;
    atomicAdd(&deg[b * NN + ei[(size_t)b * 2 * EE + e]], ew[(size_t)b * EE + e]);
}

__global__ __launch_bounds__(256) void deginv_kernel(const float* __restrict__ deg, float* __restrict__ dinv) {
    int i = blockIdx.x * 256 + threadIdx.x;
    if (i < BB * NN) {
        float d = deg[i];
        dinv[i] = (d > 0.0f) ? rsqrtf(d) : 0.0f;
    }
}

__global__ __launch_bounds__(256) void gemm_f32src_kernel(const float* __restrict__ x, const _Float16* __restrict__ wt,
                                                          _Float16* __restrict__ xw) {
    __shared__ _Float16 As[128][64];
    __shared__ _Float16 Bs[128][64];
    int tid = threadIdx.x;
    int lane = tid & 63;
    int wave = tid >> 6;
    int row0 = blockIdx.x * 128;
    int col0 = blockIdx.y * 128;
    int wr = wave >> 1, wc = wave & 1;
    int hi = lane >> 4, lo = lane & 15;
    f32x4 acc[4][4] = {};
    for (int kk = 0; kk < CIN; kk += 64) {
        #pragma unroll
        for (int j = 0; j < 4; ++j) {
            int c = j * 256 + tid;
            int r = c >> 3, kq = c & 7;
            const float* g = &x[(size_t)(row0 + r) * CIN + kk + 8 * kq];
            float4 f0 = *reinterpret_cast<const float4*>(g);
            float4 f1 = *reinterpret_cast<const float4*>(g + 4);
            h16x8 v;
            v[0] = (_Float16)f0.x; v[1] = (_Float16)f0.y; v[2] = (_Float16)f0.z; v[3] = (_Float16)f0.w;
            v[4] = (_Float16)f1.x; v[5] = (_Float16)f1.y; v[6] = (_Float16)f1.z; v[7] = (_Float16)f1.w;
            *reinterpret_cast<h16x8*>(&As[r][8 * kq]) = v;
        }
        #pragma unroll
        for (int j = 0; j < 4; ++j) {
            int c = j * 256 + tid;
            int r = c >> 3, kq = c & 7;
            *reinterpret_cast<h16x8*>(&Bs[r][8 * kq]) =
                *reinterpret_cast<const h16x8*>(&wt[(size_t)(col0 + r) * CIN + kk + 8 * kq]);
        }
        __syncthreads();
        #pragma unroll
        for (int ks = 0; ks < 2; ++ks) {
            h16x8 a[4], b[4];
            #pragma unroll
            for (int m = 0; m < 4; ++m)
                a[m] = *reinterpret_cast<const h16x8*>(&As[wr * 64 + m * 16 + lo][ks * 32 + 8 * hi]);
            #pragma unroll
            for (int n = 0; n < 4; ++n)
                b[n] = *reinterpret_cast<const h16x8*>(&Bs[wc * 64 + n * 16 + lo][ks * 32 + 8 * hi]);
            #pragma unroll
            for (int m = 0; m < 4; ++m)
                #pragma unroll
                for (int n = 0; n < 4; ++n)
                    acc[m][n] = __builtin_amdgcn_mfma_f32_16x16x32_f16(a[m], b[n], acc[m][n], 0, 0, 0);
        }
        __syncthreads();
    }
    #pragma unroll
    for (int m = 0; m < 4; ++m)
        #pragma unroll
        for (int n = 0; n < 4; ++n)
            #pragma unroll
            for (int r = 0; r < 4; ++r) {
                int row = row0 + wr * 64 + m * 16 + hi * 4 + r;
                int col = col0 + wc * 64 + n * 16 + lo;
                xw[(size_t)row * COUT + col] = (_Float16)acc[m][n][r];
            }
}

__global__ __launch_bounds__(256) void self_kernel(const _Float16* __restrict__ xw, const float* __restrict__ dinv,
                                                   float* __restrict__ out) {
    int bn = blockIdx.x;
    int c = threadIdx.x;
    float di = dinv[bn];
    out[(size_t)bn * COUT + c] = di * di * (float)xw[(size_t)bn * COUT + c];
}

__global__ __launch_bounds__(256) void scatter_atomic_kernel(const int* __restrict__ ei, const float* __restrict__ ew,
                                                             const float* __restrict__ dinv,
                                                             const _Float16* __restrict__ xw, float* __restrict__ out) {
    int be = blockIdx.x;
    int b = be / EE, e = be - b * EE;
    int c = threadIdx.x;
    int row = ei[(size_t)b * 2 * EE + e];
    int col = ei[(size_t)b * 2 * EE + EE + e];
    float w = ew[(size_t)b * EE + e];
    float nm = dinv[b * NN + row] * w * dinv[b * NN + col];
    const _Float16* xwb = xw + (size_t)b * NN * COUT;
    atomicAdd(&out[((size_t)b * NN + row) * COUT + c], nm * (float)xwb[(size_t)col * COUT + c]);
}

__global__ __launch_bounds__(256) void relu_kernel(float* __restrict__ out) {
    size_t i = (size_t)blockIdx.x * 256 + threadIdx.x;
    out[i] = fmaxf(out[i], 0.0f);
}

extern "C" void kernel_launch(void* const* d_in, const int* in_sizes, int n_in,
                              void* d_out, int out_size, void* d_ws, size_t ws_size,
                              hipStream_t stream) {
    const float* x  = (const float*)d_in[0];
    const int*   ei = (const int*)d_in[1];
    const float* ew = (const float*)d_in[2];
    const float* Wm = (const float*)d_in[3];
    float* out = (float*)d_out;

    char* ws = (char*)d_ws;
    size_t off = 0;
    auto alloc = [&](size_t bytes) -> void* {
        void* p = ws + off;
        off += (bytes + 255) & ~(size_t)255;
        return p;
    };
    _Float16* xw        = (_Float16*)alloc((size_t)BB * NN * COUT * 2);   // 32 MB
    _Float16* xh        = (_Float16*)alloc((size_t)BB * NN * CIN * 2);    // 32 MB
    int*      chist     = (int*)alloc((size_t)BB * NCH * NN * 4);         // 4 MB
    float*    wdeg      = (float*)alloc((size_t)BB * NCH * NN * 4);       // 4 MB
    int*      chunkbase = (int*)alloc((size_t)BB * NCH * NN * 4);         // 4 MB
    int*      roff      = (int*)alloc((size_t)BB * NN * 4);               // 256 KB
    float*    dinv      = (float*)alloc((size_t)BB * NN * 4);             // 256 KB
    _Float16* wt        = (_Float16*)alloc((size_t)CIN * COUT * 2);
    int2*     csr       = (int2*)xh;        // alias: xh dead after gemm DISPATCH completes; csr written in a LATER dispatch
    float*    deg_fb    = (float*)chist;    // fallback-only alias
    bool use_csr = (ws_size >= off);

    if (use_csr) {
        const int xcvtBlocks = (BB * NN * CIN) / (256 * 8);   // 8192
        phaseA_kernel<<<BB * NCH + xcvtBlocks + COUT, 256, 0, stream>>>(x, xh, Wm, wt, ei, ew, chist, wdeg);
        scanfused_kernel<<<BB, 1024, 0, stream>>>(chist, wdeg, chunkbase, roff, dinv);
        gemm_glds_kernel<<<(BB * NN / 128) * (COUT / 128), 256, 0, stream>>>(xh, wt, xw);
        scatter2_kernel<<<BB * NCH, 256, 0, stream>>>(ei, ew, dinv, chunkbase, csr);
        aggregate_kernel<<<BB * NN / 4, 256, 0, stream>>>(xw, dinv, roff, csr, out);
    } else {
        const int bnBlocks = (BB * NN) / 256;
        cvt_wt_kernel<<<COUT, CIN, 0, stream>>>(Wm, wt);
        init_deg_kernel<<<bnBlocks, 256, 0, stream>>>(deg_fb, 1.0f);
        deg_only_kernel<<<(BB * EE) / 256, 256, 0, stream>>>(ei, ew, deg_fb);
        deginv_kernel<<<bnBlocks, 256, 0, stream>>>(deg_fb, dinv);
        dim3 ggrid((BB * NN) / 128, COUT / 128);
        gemm_f32src_kernel<<<ggrid, 256, 0, stream>>>(x, wt, xw);
        self_kernel<<<BB * NN, 256, 0, stream>>>(xw, dinv, out);
        scatter_atomic_kernel<<<BB * EE, 256, 0, stream>>>(ei, ew, dinv, xw, out);
        relu_kernel<<<(BB * NN * COUT) / 256, 256, 0, stream>>>(out);
    }
}